// Round 6
// baseline (205.076 us; speedup 1.0000x reference)
//
#include <hip/hip_runtime.h>

// SaltAndPepper: out = where(mask==0, 0, where(mask==1, 1, image))
// image: (32,3,512,512) f32, mask: (32,1,512,512) i32 broadcast over C.
//
// History: R2 one-group/thread 63.5us (3.7 TB/s effective cache-level).
// R4 unroll x4 + nontemporal stores REGRESSED to ~70.5us -> NT dropped.
// R5: persistent grid at exact max occupancy (2048 blocks = 8/CU, 32
// waves/CU), block-chunked: each block owns 3072 contiguous groups, each
// thread 12 groups in 3 batches of 4 (loads issued before stores in each
// batch; ~32 live VGPRs keeps full occupancy). Plain global stores.

constexpr int B  = 32;
constexpr int C  = 3;
constexpr int HW = 512 * 512;                 // 262144 pixels per plane
constexpr int G_PER_PLANE = HW / 4;           // 65536 float4 groups (2^16)
constexpr int TOTAL_G = B * C * G_PER_PLANE;  // 6,291,456
constexpr int BLOCK   = 256;
constexpr int GRID    = 2048;                 // 8 blocks/CU on 256 CUs
constexpr int G_PER_BLOCK = TOTAL_G / GRID;   // 3072
constexpr int U       = 4;                    // groups per batch
constexpr int ITERS   = G_PER_BLOCK / (BLOCK * U);  // 3

typedef float f4 __attribute__((ext_vector_type(4)));
typedef int   i4 __attribute__((ext_vector_type(4)));

__global__ __launch_bounds__(BLOCK)
void sp_kernel(const float* __restrict__ img,
               const int*   __restrict__ mask,
               float*       __restrict__ out) {
    const int blockBase = blockIdx.x * G_PER_BLOCK + threadIdx.x;

    #pragma unroll
    for (int i = 0; i < ITERS; ++i) {
        int t[U];
        i4  m[U];
        f4  v[U];

        #pragma unroll
        for (int k = 0; k < U; ++k) {
            t[k] = blockBase + (i * U + k) * BLOCK;   // coalesced per wave
            const int plane = t[k] >> 16;             // b*C + c, in [0,96)
            const int b     = plane / 3;
            const int g     = t[k] & (G_PER_PLANE - 1);
            m[k] = *(const i4*)(mask + (size_t)b * HW + (size_t)g * 4);
            v[k] = *(const f4*)(img + (size_t)t[k] * 4);
        }

        #pragma unroll
        for (int k = 0; k < U; ++k) {
            f4 r;
            r.x = (m[k].x == 0) ? 0.0f : ((m[k].x == 1) ? 1.0f : v[k].x);
            r.y = (m[k].y == 0) ? 0.0f : ((m[k].y == 1) ? 1.0f : v[k].y);
            r.z = (m[k].z == 0) ? 0.0f : ((m[k].z == 1) ? 1.0f : v[k].z);
            r.w = (m[k].w == 0) ? 0.0f : ((m[k].w == 1) ? 1.0f : v[k].w);
            *(f4*)(out + (size_t)t[k] * 4) = r;
        }
    }
}

extern "C" void kernel_launch(void* const* d_in, const int* in_sizes, int n_in,
                              void* d_out, int out_size, void* d_ws, size_t ws_size,
                              hipStream_t stream) {
    const float* img  = (const float*)d_in[0];
    const int*   mask = (const int*)d_in[1];
    float*       out  = (float*)d_out;

    sp_kernel<<<GRID, BLOCK, 0, stream>>>(img, mask, out);
}

// Round 7
// 198.473 us; speedup vs baseline: 1.0333x; 1.0333x over previous
//
#include <hip/hip_runtime.h>

// SaltAndPepper: out = where(mask==0, 0, where(mask==1, 1, image))
// image: (32,3,512,512) f32, mask: (32,1,512,512) i32 broadcast over C.
//
// History: R2 (1 float4 group/thread) = 63.5us/dispatch, fabric 2.6 TB/s.
// R4 (unroll4+NT stores) 70.5us REGRESS. R5 (persistent grid) 75.5us
// REGRESS, FETCH 64->96 MB (persistent layout kills L3 warmth from the
// harness's input-restore). Model: all variants pin at ~2.6 TB/s fabric;
// adding the harness's ~200 MB dirty-L3 drain (d_in restore + d_out poison
// right before each replay) the HBM is actually near the 6.3 TB/s ceiling.
// R6 experiment: mask-once structure — one thread owns one mask int4 and
// all 3 channels (cuts L2-level mask reads 3x, 7 mem ops per 3 outputs
// instead of 9). Neutral under drain theory, -15% under L2-rate theory.

constexpr int B  = 32;
constexpr int C  = 3;
constexpr int HW = 512 * 512;              // 262144 pixels per plane
constexpr int G_PER_B = HW / 4;            // 65536 groups per batch (2^16)
constexpr int TOTAL_T = B * G_PER_B;       // 2,097,152 threads
constexpr int BLOCK = 256;

typedef float f4 __attribute__((ext_vector_type(4)));
typedef int   i4 __attribute__((ext_vector_type(4)));

__global__ __launch_bounds__(BLOCK)
void sp_kernel(const float* __restrict__ img,
               const int*   __restrict__ mask,
               float*       __restrict__ out) {
    const int t = blockIdx.x * BLOCK + threadIdx.x;   // one per mask int4
    const int b = t >> 16;                 // batch index, [0,32)
    const int g = t & (G_PER_B - 1);       // group within plane

    const i4 m = *(const i4*)(mask + (size_t)b * HW + (size_t)g * 4);

    const size_t base = (size_t)b * (C * HW) + (size_t)g * 4;

    f4 v[C];
    #pragma unroll
    for (int c = 0; c < C; ++c)            // all loads before any store
        v[c] = *(const f4*)(img + base + (size_t)c * HW);

    #pragma unroll
    for (int c = 0; c < C; ++c) {
        f4 r;
        r.x = (m.x == 0) ? 0.0f : ((m.x == 1) ? 1.0f : v[c].x);
        r.y = (m.y == 0) ? 0.0f : ((m.y == 1) ? 1.0f : v[c].y);
        r.z = (m.z == 0) ? 0.0f : ((m.z == 1) ? 1.0f : v[c].z);
        r.w = (m.w == 0) ? 0.0f : ((m.w == 1) ? 1.0f : v[c].w);
        *(f4*)(out + base + (size_t)c * HW) = r;
    }
}

extern "C" void kernel_launch(void* const* d_in, const int* in_sizes, int n_in,
                              void* d_out, int out_size, void* d_ws, size_t ws_size,
                              hipStream_t stream) {
    const float* img  = (const float*)d_in[0];
    const int*   mask = (const int*)d_in[1];
    float*       out  = (float*)d_out;

    sp_kernel<<<TOTAL_T / BLOCK, BLOCK, 0, stream>>>(img, mask, out);
}

// Round 8
// 195.279 us; speedup vs baseline: 1.0502x; 1.0164x over previous
//
#include <hip/hip_runtime.h>

// SaltAndPepper: out = where(mask==0, 0, where(mask==1, 1, image))
// image: (32,3,512,512) f32, mask: (32,1,512,512) i32 broadcast over C.
//
// FINAL (revert to R2 = best measured). Experiment ledger:
//   R2  1 float4-group/thread, linear streams        63.5 us  <-- best
//   R4  unroll x4 + nontemporal stores               70.5 us  regress
//   R5  persistent grid (2048 blocks, 12 grp/thread) 75.5 us  regress (+50% FETCH)
//   R6  mask-once, 3 channels/thread                 70.5 us  regress
// Model: all variants pin at ~2.6 TB/s kernel-observed fabric. The harness
// restores d_in (128 MB) and poisons d_out (96 MB) right before each graph
// replay, leaving ~200 MB of dirty L3 lines that drain to HBM during our
// kernel; counting the drain, HBM runs at ~5.7 TB/s ~= the 6.3 TB/s copy
// ceiling. Traffic is irreducible (image 96 + mask 32 + out 96 MiB; mask
// line-granularity sparsity ~0.15% -> conditional image reads useless).
// This is the effective roofline for this harness.

constexpr int B  = 32;
constexpr int C  = 3;
constexpr int HW = 512 * 512;              // 262144 pixels per plane
constexpr int G_PER_PLANE = HW / 4;        // 65536 float4 groups (2^16)
constexpr int TOTAL_G = B * C * G_PER_PLANE;  // 6,291,456

__global__ __launch_bounds__(256)
void sp_kernel(const float* __restrict__ img,
               const int*   __restrict__ mask,
               float*       __restrict__ out) {
    const int t = blockIdx.x * blockDim.x + threadIdx.x;  // one per out float4
    if (t >= TOTAL_G) return;

    const int plane = t >> 16;        // b*C + c, in [0, 96)
    const int b     = plane / 3;      // magic-mul, cheap
    const int g     = t & (G_PER_PLANE - 1);

    const int4 m = *(const int4*)(mask + (size_t)b * HW + (size_t)g * 4);

    const size_t off = (size_t)t * 4;   // linear over image/out
    const float4 v = *(const float4*)(img + off);

    float4 r;
    r.x = (m.x == 0) ? 0.0f : ((m.x == 1) ? 1.0f : v.x);
    r.y = (m.y == 0) ? 0.0f : ((m.y == 1) ? 1.0f : v.y);
    r.z = (m.z == 0) ? 0.0f : ((m.z == 1) ? 1.0f : v.z);
    r.w = (m.w == 0) ? 0.0f : ((m.w == 1) ? 1.0f : v.w);
    *(float4*)(out + off) = r;
}

extern "C" void kernel_launch(void* const* d_in, const int* in_sizes, int n_in,
                              void* d_out, int out_size, void* d_ws, size_t ws_size,
                              hipStream_t stream) {
    const float* img  = (const float*)d_in[0];
    const int*   mask = (const int*)d_in[1];
    float*       out  = (float*)d_out;

    const int block = 256;
    const int grid  = TOTAL_G / block;   // 24576 blocks, exact
    sp_kernel<<<grid, block, 0, stream>>>(img, mask, out);
}